// Round 1
// baseline (12758.469 us; speedup 1.0000x reference)
//
#include <hip/hip_runtime.h>

typedef unsigned short u16;
typedef __attribute__((ext_vector_type(8))) short short8;
typedef __attribute__((ext_vector_type(4))) float f32x4;
typedef __attribute__((ext_vector_type(4))) int i32x4;
typedef __attribute__((ext_vector_type(4))) unsigned short u16x4;

#define NN 307      // nodes
#define NP 320      // padded nodes (K and N of GEMM)
#define TT 64       // time steps
#define LDP 76      // fp32 LDS row stride ([64][76], 16B aligned rows, bank-spread)
#define LWS 68      // fp32 LDS row stride for 64x64 weight matrices
#define LNEPS 1e-5f

__device__ __forceinline__ u16 f2bf(float f) {
  union { float f; unsigned u; } v; v.f = f;
  unsigned r = (v.u + 0x7FFFu + ((v.u >> 16) & 1u)) >> 16;  // RNE
  return (u16)r;
}
__device__ __forceinline__ float bf2f(u16 h) {
  union { unsigned u; float f; } v; v.u = ((unsigned)h) << 16;
  return v.f;
}
__device__ __forceinline__ void split3(float v, u16 &h, u16 &m, u16 &l) {
  h = f2bf(v);
  float r1 = v - bf2f(h);
  m = f2bf(r1);
  float r2 = r1 - bf2f(m);
  l = f2bf(r2);
}

#define MFMA(a, b, c) __builtin_amdgcn_mfma_f32_16x16x32_bf16((a), (b), (c), 0, 0, 0)

// ---------------------------------------------------------------------------
// GEMM core: acc[c-tile 64][n-tile 64] = sum_k X[c][k] * Amat[n][k]
// (A symmetric -> Amat[n][k] = A[k][n], so this is A @ Z in node space)
// X,A are 3-way bf16 splits; 6 products kept -> ~fp32 accuracy.
// Per-lane direct global loads (contiguous 16B along K per lane; a 16-lane
// group + 4 k-slots covers full 64B lines). No LDS, no syncs in K-loop.
// MFMA layouts (gfx950 16x16x32):
//   A-op: lane holds A[l&15][8*(l>>4)+i] ; B-op: B[8*(l>>4)+i][l&15]
//   C/D : col = l&15, row = 4*(l>>4)+i   (m89-verified)
// ---------------------------------------------------------------------------
__device__ __forceinline__ void gemm_block(
    const u16* __restrict__ A_hi, const u16* __restrict__ A_md, const u16* __restrict__ A_lo,
    const u16* __restrict__ X_hi, const u16* __restrict__ X_md, const u16* __restrict__ X_lo,
    int c0, int n0, int tid, f32x4 acc[2][2])
{
  const int w = tid >> 6, l = tid & 63, lr = l & 15, lg = l >> 4;
  const int wr = w >> 1, wc = w & 1;
  const size_t xr0 = (size_t)(c0 + wr * 32 + lr) * NP;
  const size_t xr1 = xr0 + (size_t)16 * NP;
  const size_t ar0 = (size_t)(n0 + wc * 32 + lr) * NP;
  const size_t ar1 = ar0 + (size_t)16 * NP;
  for (int kk = 0; kk < 10; ++kk) {
    const int ko = kk * 32 + lg * 8;
    short8 xh[2], xm[2], xl[2], ah[2], am[2], al[2];
    xh[0] = *(const short8*)&X_hi[xr0 + ko];
    xm[0] = *(const short8*)&X_md[xr0 + ko];
    xl[0] = *(const short8*)&X_lo[xr0 + ko];
    xh[1] = *(const short8*)&X_hi[xr1 + ko];
    xm[1] = *(const short8*)&X_md[xr1 + ko];
    xl[1] = *(const short8*)&X_lo[xr1 + ko];
    ah[0] = *(const short8*)&A_hi[ar0 + ko];
    am[0] = *(const short8*)&A_md[ar0 + ko];
    al[0] = *(const short8*)&A_lo[ar0 + ko];
    ah[1] = *(const short8*)&A_hi[ar1 + ko];
    am[1] = *(const short8*)&A_md[ar1 + ko];
    al[1] = *(const short8*)&A_lo[ar1 + ko];
#pragma unroll
    for (int fr = 0; fr < 2; ++fr) {
#pragma unroll
      for (int fc = 0; fc < 2; ++fc) {
        f32x4 a = acc[fr][fc];
        a = MFMA(xh[fr], ah[fc], a);   // hi*hi
        a = MFMA(xh[fr], am[fc], a);   // hi*md
        a = MFMA(xm[fr], ah[fc], a);   // md*hi
        a = MFMA(xh[fr], al[fc], a);   // hi*lo
        a = MFMA(xl[fr], ah[fc], a);   // lo*hi
        a = MFMA(xm[fr], am[fc], a);   // md*md   (dropped terms ~2^-34)
        acc[fr][fc] = a;
      }
    }
  }
}

// Write GEMM fragments to LDS as fp32 [n][d] with quad XOR swizzle.
__device__ __forceinline__ void store_G(f32x4 acc[2][2], float* ldsG, int tid) {
  const int w = tid >> 6, l = tid & 63, lr = l & 15, lg = l >> 4;
  const int wr = w >> 1, wc = w & 1;
#pragma unroll
  for (int fr = 0; fr < 2; ++fr) {
#pragma unroll
    for (int fc = 0; fc < 2; ++fc) {
      const int nn = wc * 32 + fc * 16 + lr;
      const int quad = (8 * wr + 4 * fr + lg) ^ (nn & 15);
      *(f32x4*)&ldsG[nn * LDP + quad * 4] = acc[fr][fc];
    }
  }
}

// o[j][c] = sum_d ldsG[4nq+j][d] * ldsW[d][4dq+c]   (fp32, exact)
__device__ __forceinline__ void mat64(const float* ldsG, const float* ldsW,
                                      int nq, int dq, float o[4][4]) {
#pragma unroll
  for (int j = 0; j < 4; ++j)
#pragma unroll
    for (int c = 0; c < 4; ++c) o[j][c] = 0.f;
  for (int d4 = 0; d4 < 16; ++d4) {
    f32x4 gr[4], wv[4];
#pragma unroll
    for (int j = 0; j < 4; ++j) {
      const int nl = nq * 4 + j;
      gr[j] = *(const f32x4*)&ldsG[nl * LDP + ((d4 ^ (nl & 15)) << 2)];
    }
#pragma unroll
    for (int m = 0; m < 4; ++m)
      wv[m] = *(const f32x4*)&ldsW[(d4 * 4 + m) * LWS + dq * 4];
#pragma unroll
    for (int j = 0; j < 4; ++j) {
#pragma unroll
      for (int m = 0; m < 4; ++m) {
        const float zz = gr[j][m];
#pragma unroll
        for (int c = 0; c < 4; ++c) o[j][c] += zz * wv[m][c];
      }
    }
  }
}

__device__ __forceinline__ void stage_W(const float* __restrict__ W, float* ldsW, int tid) {
  const int d = tid >> 2, ch = (tid & 3) << 4;
#pragma unroll
  for (int j = 0; j < 16; ++j)
    ldsW[d * LWS + ch + j] = W[d * 64 + ch + j];
}

// ---------------------------------------------------------------------------
// prep: split A into 3x bf16 (zero-padded 320x320); fold Wf = W_obs @ Wg_bot,
// bfold = b_obs @ Wg_bot.
// ---------------------------------------------------------------------------
__global__ __launch_bounds__(256) void k_prep(
    const float* __restrict__ A, const float* __restrict__ W_obs,
    const float* __restrict__ b_obs, const float* __restrict__ W_gate,
    u16* __restrict__ A_hi, u16* __restrict__ A_md, u16* __restrict__ A_lo,
    float* __restrict__ Wf, float* __restrict__ bfold)
{
  if (blockIdx.x < 400) {
    const int e = blockIdx.x * 256 + threadIdx.x;
    const int r = e / NP, c = e - r * NP;
    const float a = (r < NN && c < NN) ? A[r * NN + c] : 0.f;
    u16 h, m, l;
    split3(a, h, m, l);
    A_hi[e] = h; A_md[e] = m; A_lo[e] = l;
  } else if (threadIdx.x < 64) {
    const int dp = threadIdx.x;
    float s0 = 0.f, s1 = 0.f, s2 = 0.f, sb = 0.f;
    for (int d = 0; d < 64; ++d) {
      const float wg = W_gate[(64 + d) * 64 + dp];
      s0 += W_obs[d] * wg;
      s1 += W_obs[64 + d] * wg;
      s2 += W_obs[128 + d] * wg;
      sb += b_obs[d] * wg;
    }
    Wf[dp] = s0; Wf[64 + dp] = s1; Wf[128 + dp] = s2; bfold[dp] = sb;
  }
}

// ---------------------------------------------------------------------------
// init: z0 = x[:,:,0,:] @ W_enc + b_enc ; write zf + 3-split z ; pred[...,0]
// Also zero-writes the n>=307 pad (keeps GEMM K-pad clean every call).
// ---------------------------------------------------------------------------
__global__ __launch_bounds__(256) void k_init(
    const float* __restrict__ x_seq, const float* __restrict__ W_enc,
    const float* __restrict__ b_enc, const float* __restrict__ W_dec,
    const float* __restrict__ b_dec,
    float* __restrict__ zf,
    u16* __restrict__ Z_hi, u16* __restrict__ Z_md, u16* __restrict__ Z_lo,
    float* __restrict__ out)
{
  const int b = blockIdx.x, n0 = blockIdx.y * 64;
  const int tid = threadIdx.x;
  __shared__ float xs[256], we[192], be[64], wd[64];
  __shared__ float ldsR[16 * 64];
  if (tid < 64) {
    const int n = n0 + tid;
    float x0 = 0.f, x1 = 0.f, x2 = 0.f;
    if (n < NN) {
      const size_t xo = ((size_t)(b * NN + n) * TT + 0) * 3;
      x0 = x_seq[xo]; x1 = x_seq[xo + 1]; x2 = x_seq[xo + 2];
    }
    xs[tid * 4] = x0; xs[tid * 4 + 1] = x1; xs[tid * 4 + 2] = x2; xs[tid * 4 + 3] = 0.f;
    be[tid] = b_enc[tid]; wd[tid] = W_dec[tid];
  } else {
    const int e = tid - 64;
    if (e < 192) we[e] = W_enc[e];
  }
  __syncthreads();
  const int nq = tid & 15, dq = tid >> 4;
  float zn[4][4];
  float p[4] = {0.f, 0.f, 0.f, 0.f};
#pragma unroll
  for (int j = 0; j < 4; ++j) {
    const int nl = nq * 4 + j;
    const bool v = (n0 + nl) < NN;
    const float x0 = xs[nl * 4], x1 = xs[nl * 4 + 1], x2 = xs[nl * 4 + 2];
#pragma unroll
    for (int c = 0; c < 4; ++c) {
      const int d = dq * 4 + c;
      float z = x0 * we[d] + x1 * we[64 + d] + x2 * we[128 + d] + be[d];
      z = v ? z : 0.f;
      zn[j][c] = z;
      p[j] += z * wd[d];
    }
  }
#pragma unroll
  for (int c = 0; c < 4; ++c) {
    const int d = dq * 4 + c;
    const size_t off = (size_t)(b * 64 + d) * NP + n0 + nq * 4;
    f32x4 vf = { zn[0][c], zn[1][c], zn[2][c], zn[3][c] };
    *(f32x4*)&zf[off] = vf;
    u16x4 vh, vm, vl;
#pragma unroll
    for (int j = 0; j < 4; ++j) {
      u16 hh, mm2, ll;
      split3(zn[j][c], hh, mm2, ll);
      vh[j] = hh; vm[j] = mm2; vl[j] = ll;
    }
    *(u16x4*)&Z_hi[off] = vh;
    *(u16x4*)&Z_md[off] = vm;
    *(u16x4*)&Z_lo[off] = vl;
  }
#pragma unroll
  for (int j = 0; j < 4; ++j) ldsR[dq * 64 + nq * 4 + j] = p[j];
  __syncthreads();
  if (tid < 64) {
    const int n = n0 + tid;
    if (n < NN) {
      float s = 0.f;
#pragma unroll
      for (int q = 0; q < 16; ++q) s += ldsR[q * 64 + tid];
      out[(size_t)(b * NN + n) * TT + 0] = s + b_dec[0];
    }
  }
}

// ---------------------------------------------------------------------------
// step1: h1 = tanh((A @ z) @ W_gc1), written as 3-split bf16 in [c][n] layout.
// ---------------------------------------------------------------------------
__global__ __launch_bounds__(256) void k_step1(
    const u16* __restrict__ A_hi, const u16* __restrict__ A_md, const u16* __restrict__ A_lo,
    const u16* __restrict__ X_hi, const u16* __restrict__ X_md, const u16* __restrict__ X_lo,
    const float* __restrict__ W_gc1,
    u16* __restrict__ O_hi, u16* __restrict__ O_md, u16* __restrict__ O_lo)
{
  const int b = blockIdx.x, n0 = blockIdx.y * 64, c0 = b * 64;
  const int tid = threadIdx.x;
  __shared__ __align__(16) float ldsG[64 * LDP];
  __shared__ __align__(16) float ldsW[64 * LWS];
  stage_W(W_gc1, ldsW, tid);
  f32x4 acc[2][2];
  acc[0][0] = 0.f; acc[0][1] = 0.f; acc[1][0] = 0.f; acc[1][1] = 0.f;
  gemm_block(A_hi, A_md, A_lo, X_hi, X_md, X_lo, c0, n0, tid, acc);
  store_G(acc, ldsG, tid);
  __syncthreads();
  const int nq = tid & 15, dq = tid >> 4;
  float mx[4][4];
  mat64(ldsG, ldsW, nq, dq, mx);
#pragma unroll
  for (int c = 0; c < 4; ++c) {
    u16x4 vh, vm, vl;
#pragma unroll
    for (int j = 0; j < 4; ++j) {
      const float v = tanhf(mx[j][c]);
      u16 hh, mm2, ll;
      split3(v, hh, mm2, ll);
      vh[j] = hh; vm[j] = mm2; vl[j] = ll;
    }
    const size_t off = (size_t)(c0 + dq * 4 + c) * NP + n0 + nq * 4;
    *(u16x4*)&O_hi[off] = vh;
    *(u16x4*)&O_md[off] = vm;
    *(u16x4*)&O_lo[off] = vl;
  }
}

// ---------------------------------------------------------------------------
// step2: h2 = tanh((A @ h1) @ W_gc2); delta = LN(h2); z' = 2z + delta;
// gate = sigmoid(z'@Wg_top + x@Wf + bfold + b_gate)  [all fp32];
// z_new = z' + gate*(z_obs - z')*mask ; write zf + 3-split z ; pred[..., t+1]
// ---------------------------------------------------------------------------
__global__ __launch_bounds__(256) void k_step2(
    const u16* __restrict__ A_hi, const u16* __restrict__ A_md, const u16* __restrict__ A_lo,
    const u16* __restrict__ X_hi, const u16* __restrict__ X_md, const u16* __restrict__ X_lo,
    const float* __restrict__ W_gc2,
    const float* __restrict__ x_seq, const float* __restrict__ obs_mask,
    const float* __restrict__ W_gate, const float* __restrict__ b_gate,
    const float* __restrict__ ln_g, const float* __restrict__ ln_b,
    const float* __restrict__ W_obs, const float* __restrict__ b_obs,
    const float* __restrict__ Wf, const float* __restrict__ bfold,
    const float* __restrict__ W_dec, const float* __restrict__ b_dec,
    float* __restrict__ zf,
    u16* __restrict__ Z_hi, u16* __restrict__ Z_md, u16* __restrict__ Z_lo,
    float* __restrict__ out, int t)
{
  const int b = blockIdx.x, n0 = blockIdx.y * 64, c0 = b * 64;
  const int tid = threadIdx.x;
  __shared__ __align__(16) float ldsG[64 * LDP];   // G, then z' (reused)
  __shared__ __align__(16) float ldsW[64 * LWS];   // W_gc2
  __shared__ __align__(16) float ldsWg[64 * LWS];  // W_gate top half
  __shared__ float ldsR[16 * 64];
  __shared__ float ldsMu[64], ldsRs[64];
  __shared__ float sLng[64], sLnb[64], sWd[64], sBg[64], sBo[64], sBf[64], sMask[64];
  __shared__ float sWo[192], sWfl[192], sXv[256];

  stage_W(W_gc2, ldsW, tid);
  stage_W(W_gate, ldsWg, tid);   // rows 0..63 of (128,64) = Wg_top
  if (tid < 64) {
    sLng[tid] = ln_g[tid]; sLnb[tid] = ln_b[tid]; sWd[tid] = W_dec[tid];
    sBg[tid] = b_gate[tid]; sBo[tid] = b_obs[tid]; sBf[tid] = bfold[tid];
    const int n = n0 + tid;
    sMask[tid] = (n < NN) ? obs_mask[b * NN + n] : 0.f;
    float x0 = 0.f, x1 = 0.f, x2 = 0.f;
    if (n < NN) {
      const size_t xo = ((size_t)(b * NN + n) * TT + (t + 1)) * 3;
      x0 = x_seq[xo]; x1 = x_seq[xo + 1]; x2 = x_seq[xo + 2];
    }
    sXv[tid * 4] = x0; sXv[tid * 4 + 1] = x1; sXv[tid * 4 + 2] = x2; sXv[tid * 4 + 3] = 0.f;
  } else {
    const int e = tid - 64;
    if (e < 192) { sWo[e] = W_obs[e]; sWfl[e] = Wf[e]; }
  }

  f32x4 acc[2][2];
  acc[0][0] = 0.f; acc[0][1] = 0.f; acc[1][0] = 0.f; acc[1][1] = 0.f;
  gemm_block(A_hi, A_md, A_lo, X_hi, X_md, X_lo, c0, n0, tid, acc);
  store_G(acc, ldsG, tid);
  __syncthreads();

  const int nq = tid & 15, dq = tid >> 4;
  float mx[4][4];
  mat64(ldsG, ldsW, nq, dq, mx);
  float h2[4][4];
#pragma unroll
  for (int j = 0; j < 4; ++j)
#pragma unroll
    for (int c = 0; c < 4; ++c) h2[j][c] = tanhf(mx[j][c]);

  // LayerNorm over d' (two-pass, matches reference)
#pragma unroll
  for (int j = 0; j < 4; ++j)
    ldsR[dq * 64 + nq * 4 + j] = h2[j][0] + h2[j][1] + h2[j][2] + h2[j][3];
  __syncthreads();
  if (tid < 64) {
    float s = 0.f;
#pragma unroll
    for (int q = 0; q < 16; ++q) s += ldsR[q * 64 + tid];
    ldsMu[tid] = s * (1.f / 64.f);
  }
  __syncthreads();
#pragma unroll
  for (int j = 0; j < 4; ++j) {
    const float mu = ldsMu[nq * 4 + j];
    float qq = 0.f;
#pragma unroll
    for (int c = 0; c < 4; ++c) { const float dd = h2[j][c] - mu; qq += dd * dd; }
    ldsR[dq * 64 + nq * 4 + j] = qq;
  }
  __syncthreads();
  if (tid < 64) {
    float s = 0.f;
#pragma unroll
    for (int q = 0; q < 16; ++q) s += ldsR[q * 64 + tid];
    ldsRs[tid] = rsqrtf(s * (1.f / 64.f) + LNEPS);
  }
  __syncthreads();

  // z' = 2z + delta ; store z' into ldsG (swizzled) for the gate matmul
  f32x4 zoldv[4];
#pragma unroll
  for (int c = 0; c < 4; ++c)
    zoldv[c] = *(const f32x4*)&zf[(size_t)(c0 + dq * 4 + c) * NP + n0 + nq * 4];
  float zpr[4][4];
#pragma unroll
  for (int j = 0; j < 4; ++j) {
    const int nl = nq * 4 + j;
    const float mu = ldsMu[nl], rs = ldsRs[nl];
#pragma unroll
    for (int c = 0; c < 4; ++c) {
      const int dpp = dq * 4 + c;
      const float delta = (h2[j][c] - mu) * rs * sLng[dpp] + sLnb[dpp];
      zpr[j][c] = 2.f * zoldv[c][j] + delta;
    }
    f32x4 zrow = { zpr[j][0], zpr[j][1], zpr[j][2], zpr[j][3] };
    *(f32x4*)&ldsG[nl * LDP + ((dq ^ (nl & 15)) << 2)] = zrow;
  }
  __syncthreads();

  // gate pre-sigmoid z-part (fp32 exact)
  float ps[4][4];
  mat64(ldsG, ldsWg, nq, dq, ps);

  float znew[4][4];
  float p[4] = {0.f, 0.f, 0.f, 0.f};
#pragma unroll
  for (int j = 0; j < 4; ++j) {
    const int nl = nq * 4 + j;
    const bool valid = (n0 + nl) < NN;
    const float x0 = sXv[nl * 4], x1 = sXv[nl * 4 + 1], x2 = sXv[nl * 4 + 2];
    const float mk = sMask[nl];
#pragma unroll
    for (int c = 0; c < 4; ++c) {
      const int dpp = dq * 4 + c;
      const float presig = ps[j][c] + sBg[dpp] + sBf[dpp]
          + x0 * sWfl[dpp] + x1 * sWfl[64 + dpp] + x2 * sWfl[128 + dpp];
      const float gate = 1.f / (1.f + expf(-presig));
      const float zobs = x0 * sWo[dpp] + x1 * sWo[64 + dpp] + x2 * sWo[128 + dpp] + sBo[dpp];
      float zn2 = zpr[j][c] + gate * (zobs - zpr[j][c]) * mk;
      zn2 = valid ? zn2 : 0.f;
      znew[j][c] = zn2;
      p[j] += zn2 * sWd[dpp];
    }
  }
#pragma unroll
  for (int c = 0; c < 4; ++c) {
    const size_t off = (size_t)(c0 + dq * 4 + c) * NP + n0 + nq * 4;
    f32x4 vf = { znew[0][c], znew[1][c], znew[2][c], znew[3][c] };
    *(f32x4*)&zf[off] = vf;
    u16x4 vh, vm, vl;
#pragma unroll
    for (int j = 0; j < 4; ++j) {
      u16 hh, mm2, ll;
      split3(znew[j][c], hh, mm2, ll);
      vh[j] = hh; vm[j] = mm2; vl[j] = ll;
    }
    *(u16x4*)&Z_hi[off] = vh;
    *(u16x4*)&Z_md[off] = vm;
    *(u16x4*)&Z_lo[off] = vl;
  }
#pragma unroll
  for (int j = 0; j < 4; ++j) ldsR[dq * 64 + nq * 4 + j] = p[j];
  __syncthreads();
  if (tid < 64) {
    const int n = n0 + tid;
    if (n < NN) {
      float s = 0.f;
#pragma unroll
      for (int q = 0; q < 16; ++q) s += ldsR[q * 64 + tid];
      out[(size_t)(b * NN + n) * TT + (t + 1)] = s + b_dec[0];
    }
  }
}

// ---------------------------------------------------------------------------
extern "C" void kernel_launch(void* const* d_in, const int* in_sizes, int n_in,
                              void* d_out, int out_size, void* d_ws, size_t ws_size,
                              hipStream_t stream) {
  const float* x_seq  = (const float*)d_in[0];
  const float* obs    = (const float*)d_in[1];
  const float* A      = (const float*)d_in[2];
  const float* W_enc  = (const float*)d_in[3];
  const float* b_enc  = (const float*)d_in[4];
  const float* W_gc1  = (const float*)d_in[5];
  const float* W_gc2  = (const float*)d_in[6];
  const float* ln_g   = (const float*)d_in[7];
  const float* ln_b   = (const float*)d_in[8];
  const float* W_obs  = (const float*)d_in[9];
  const float* b_obs  = (const float*)d_in[10];
  const float* W_gate = (const float*)d_in[11];
  const float* b_gate = (const float*)d_in[12];
  const float* W_dec  = (const float*)d_in[13];
  const float* b_dec  = (const float*)d_in[14];
  float* out = (float*)d_out;

  char* p = (char*)d_ws;
  u16* A_hi = (u16*)p; p += (size_t)NP * NP * 2;
  u16* A_md = (u16*)p; p += (size_t)NP * NP * 2;
  u16* A_lo = (u16*)p; p += (size_t)NP * NP * 2;
  u16* z_hi = (u16*)p; p += (size_t)4096 * NP * 2;
  u16* z_md = (u16*)p; p += (size_t)4096 * NP * 2;
  u16* z_lo = (u16*)p; p += (size_t)4096 * NP * 2;
  u16* h_hi = (u16*)p; p += (size_t)4096 * NP * 2;
  u16* h_md = (u16*)p; p += (size_t)4096 * NP * 2;
  u16* h_lo = (u16*)p; p += (size_t)4096 * NP * 2;
  float* zf = (float*)p; p += (size_t)4096 * NP * 4;
  float* Wf = (float*)p; p += 256 * 4;
  float* bfold = (float*)p; p += 64 * 4;

  dim3 grid(64, 5);   // 64 batches x 5 node-tiles
  k_prep<<<401, 256, 0, stream>>>(A, W_obs, b_obs, W_gate, A_hi, A_md, A_lo, Wf, bfold);
  k_init<<<grid, 256, 0, stream>>>(x_seq, W_enc, b_enc, W_dec, b_dec,
                                   zf, z_hi, z_md, z_lo, out);
  for (int t = 0; t < 63; ++t) {
    k_step1<<<grid, 256, 0, stream>>>(A_hi, A_md, A_lo, z_hi, z_md, z_lo, W_gc1,
                                      h_hi, h_md, h_lo);
    k_step2<<<grid, 256, 0, stream>>>(A_hi, A_md, A_lo, h_hi, h_md, h_lo, W_gc2,
                                      x_seq, obs, W_gate, b_gate, ln_g, ln_b,
                                      W_obs, b_obs, Wf, bfold, W_dec, b_dec,
                                      zf, z_hi, z_md, z_lo, out, t);
  }
  (void)in_sizes; (void)n_in; (void)out_size; (void)ws_size;
}